// Round 1
// baseline (1296.901 us; speedup 1.0000x reference)
//
#include <hip/hip_runtime.h>
#include <math.h>

#define N_NODES 50000
#define N_EDGES 600000
#define D 128
#define BN_EPS 1e-5f

// ---------------- init: deg = 1 (self-loop), stats = 0 ----------------
__global__ void init_kernel(float* __restrict__ deg, float* __restrict__ stats) {
    int i = blockIdx.x * blockDim.x + threadIdx.x;
    if (i < N_NODES) deg[i] = 1.0f;
    if (i < 4 * D) stats[i] = 0.0f;
}

// ---------------- degree accumulation ----------------
__global__ void deg_kernel(const int* __restrict__ dst, float* __restrict__ deg) {
    int e = blockIdx.x * blockDim.x + threadIdx.x;
    if (e < N_EDGES) unsafeAtomicAdd(&deg[dst[e]], 1.0f);
}

__global__ void dinv_kernel(const float* __restrict__ deg, float* __restrict__ dinv) {
    int i = blockIdx.x * blockDim.x + threadIdx.x;
    if (i < N_NODES) dinv[i] = rsqrtf(deg[i]);
}

// ---------------- GEMM: C = act(A) @ B (+bias) ----------------
// A: [M x 128], B: [128 x 128], C: [M x 128]
// BN: a -> relu(a*bn_scale[k] + bn_bias[k]) applied while staging A.
// Tile: 64 rows/block, 256 threads, each thread 8 rows x 4 cols.
template<bool BN, bool HAS_BIAS>
__global__ __launch_bounds__(256, 2) void gemm_kernel(
    const float* __restrict__ A, const float* __restrict__ B,
    const float* __restrict__ bn_scale, const float* __restrict__ bn_bias,
    const float* __restrict__ out_bias, float* __restrict__ C, int M)
{
    __shared__ float Bsh[128 * 128];   // 64 KB, whole B
    __shared__ float Ash[32][68];      // k-chunk of A, transposed, padded

    const int tid = threadIdx.x;
    const int tx = tid & 31;   // output col group (4 cols)
    const int ty = tid >> 5;   // output row group (8 rows)
    const int m0 = blockIdx.x * 64;

    // stage all of B
    {
        const float4* B4 = (const float4*)B;
        float4* Bs4 = (float4*)Bsh;
        #pragma unroll
        for (int i = 0; i < 16; ++i) {
            int idx = i * 256 + tid;
            Bs4[idx] = B4[idx];
        }
    }

    float acc[8][4];
    #pragma unroll
    for (int r = 0; r < 8; ++r)
        #pragma unroll
        for (int c = 0; c < 4; ++c) acc[r][c] = 0.0f;

    const int lr = tid >> 2;             // staging row 0..63
    int lrow = m0 + lr; if (lrow > M - 1) lrow = M - 1;   // clamp (stores guarded)
    const int cb = (tid & 3) * 8;        // staging col base within chunk

    for (int kc = 0; kc < 4; ++kc) {
        __syncthreads();
        #pragma unroll
        for (int h = 0; h < 2; ++h) {
            int c = cb + h * 4;
            int k = kc * 32 + c;
            float4 v = *(const float4*)&A[(size_t)lrow * 128 + k];
            if (BN) {
                v.x = fmaxf(v.x * bn_scale[k + 0] + bn_bias[k + 0], 0.0f);
                v.y = fmaxf(v.y * bn_scale[k + 1] + bn_bias[k + 1], 0.0f);
                v.z = fmaxf(v.z * bn_scale[k + 2] + bn_bias[k + 2], 0.0f);
                v.w = fmaxf(v.w * bn_scale[k + 3] + bn_bias[k + 3], 0.0f);
            }
            Ash[c + 0][lr] = v.x;
            Ash[c + 1][lr] = v.y;
            Ash[c + 2][lr] = v.z;
            Ash[c + 3][lr] = v.w;
        }
        __syncthreads();

        #pragma unroll
        for (int k = 0; k < 32; ++k) {
            float4 b = *(const float4*)&Bsh[(kc * 32 + k) * 128 + tx * 4];
            float4 a01 = *(const float4*)&Ash[k][ty * 8];
            float4 a23 = *(const float4*)&Ash[k][ty * 8 + 4];
            float a[8] = {a01.x, a01.y, a01.z, a01.w, a23.x, a23.y, a23.z, a23.w};
            #pragma unroll
            for (int r = 0; r < 8; ++r) {
                acc[r][0] = fmaf(a[r], b.x, acc[r][0]);
                acc[r][1] = fmaf(a[r], b.y, acc[r][1]);
                acc[r][2] = fmaf(a[r], b.z, acc[r][2]);
                acc[r][3] = fmaf(a[r], b.w, acc[r][3]);
            }
        }
    }

    float4 ob = make_float4(0.f, 0.f, 0.f, 0.f);
    if (HAS_BIAS) ob = *(const float4*)&out_bias[tx * 4];
    #pragma unroll
    for (int r = 0; r < 8; ++r) {
        int row = m0 + ty * 8 + r;
        if (row < M) {
            float4 o;
            o.x = acc[r][0] + ob.x;
            o.y = acc[r][1] + ob.y;
            o.z = acc[r][2] + ob.z;
            o.w = acc[r][3] + ob.w;
            *(float4*)&C[(size_t)row * 128 + tx * 4] = o;
        }
    }
}

// ---------------- column stats (sum, sumsq) over rows ----------------
__global__ __launch_bounds__(256) void colstats_kernel(const float* __restrict__ h,
        float* __restrict__ sum_out, float* __restrict__ sq_out) {
    const int tid = threadIdx.x;
    const int c4 = tid & 31;
    const int ro = tid >> 5;   // 0..7
    float4 sum = make_float4(0.f, 0.f, 0.f, 0.f);
    float4 sq  = make_float4(0.f, 0.f, 0.f, 0.f);
    for (int row = blockIdx.x * 8 + ro; row < N_NODES; row += gridDim.x * 8) {
        float4 v = *(const float4*)&h[(size_t)row * D + c4 * 4];
        sum.x += v.x; sum.y += v.y; sum.z += v.z; sum.w += v.w;
        sq.x = fmaf(v.x, v.x, sq.x); sq.y = fmaf(v.y, v.y, sq.y);
        sq.z = fmaf(v.z, v.z, sq.z); sq.w = fmaf(v.w, v.w, sq.w);
    }
    __shared__ float4 sS[256];
    __shared__ float4 qS[256];
    sS[tid] = sum; qS[tid] = sq;
    __syncthreads();
    if (ro == 0) {
        #pragma unroll
        for (int j = 1; j < 8; ++j) {
            float4 s2 = sS[j * 32 + c4];
            float4 q2 = qS[j * 32 + c4];
            sum.x += s2.x; sum.y += s2.y; sum.z += s2.z; sum.w += s2.w;
            sq.x += q2.x; sq.y += q2.y; sq.z += q2.z; sq.w += q2.w;
        }
        unsafeAtomicAdd(&sum_out[c4 * 4 + 0], sum.x);
        unsafeAtomicAdd(&sum_out[c4 * 4 + 1], sum.y);
        unsafeAtomicAdd(&sum_out[c4 * 4 + 2], sum.z);
        unsafeAtomicAdd(&sum_out[c4 * 4 + 3], sum.w);
        unsafeAtomicAdd(&sq_out[c4 * 4 + 0], sq.x);
        unsafeAtomicAdd(&sq_out[c4 * 4 + 1], sq.y);
        unsafeAtomicAdd(&sq_out[c4 * 4 + 2], sq.z);
        unsafeAtomicAdd(&sq_out[c4 * 4 + 3], sq.w);
    }
}

// ---------------- fold BN stats into scale/bias ----------------
__global__ void sb_kernel(const float* __restrict__ s_sum, const float* __restrict__ s_sq,
        const float* __restrict__ gamma, const float* __restrict__ beta,
        float* __restrict__ scale, float* __restrict__ bias) {
    int c = threadIdx.x;
    if (c < D) {
        const float inv_n = 1.0f / (float)N_NODES;
        float mean = s_sum[c] * inv_n;
        float var  = s_sq[c] * inv_n - mean * mean;
        float rstd = rsqrtf(var + BN_EPS);
        float sc = gamma[c] * rstd;
        scale[c] = sc;
        bias[c] = beta[c] - mean * sc;
    }
}

// ---------------- zero a float4 region ----------------
__global__ void zero_kernel(float4* __restrict__ p, int n4) {
    int i = blockIdx.x * blockDim.x + threadIdx.x;
    int stride = gridDim.x * blockDim.x;
    float4 z = make_float4(0.f, 0.f, 0.f, 0.f);
    for (; i < n4; i += stride) p[i] = z;
}

// ---------------- edge scatter: agg[dst] += dinv[s]*dinv[d]*h2[src] ----------------
__global__ __launch_bounds__(256) void agg_kernel(const int* __restrict__ srcI, const int* __restrict__ dstI,
        const float* __restrict__ dinv, const float* __restrict__ h2, float* __restrict__ agg) {
    const int t = blockIdx.x * 256 + threadIdx.x;
    const int e = t >> 5;
    const int c4 = t & 31;
    if (e >= N_EDGES) return;
    const int s = srcI[e];
    const int d = dstI[e];
    const float norm = dinv[s] * dinv[d];
    float4 v = *(const float4*)&h2[(size_t)s * D + c4 * 4];
    float* ap = &agg[(size_t)d * D + c4 * 4];
    unsafeAtomicAdd(ap + 0, norm * v.x);
    unsafeAtomicAdd(ap + 1, norm * v.y);
    unsafeAtomicAdd(ap + 2, norm * v.z);
    unsafeAtomicAdd(ap + 3, norm * v.w);
}

// ---------------- post: outpre = agg + dinv^2*h2 + b_conv; fused colstats2 ----------------
__global__ __launch_bounds__(256) void post_kernel(const float* __restrict__ agg, const float* __restrict__ h2,
        const float* __restrict__ dinv, const float* __restrict__ b_conv,
        float* __restrict__ outpre, float* __restrict__ sum_out, float* __restrict__ sq_out) {
    const int tid = threadIdx.x;
    const int c4 = tid & 31;
    const int ro = tid >> 5;
    float4 bc = *(const float4*)&b_conv[c4 * 4];
    float4 sum = make_float4(0.f, 0.f, 0.f, 0.f);
    float4 sq  = make_float4(0.f, 0.f, 0.f, 0.f);
    for (int row = blockIdx.x * 8 + ro; row < N_NODES; row += gridDim.x * 8) {
        float di = dinv[row];
        float sl = di * di;
        float4 a  = *(const float4*)&agg[(size_t)row * D + c4 * 4];
        float4 hv = *(const float4*)&h2[(size_t)row * D + c4 * 4];
        float4 o;
        o.x = a.x + sl * hv.x + bc.x;
        o.y = a.y + sl * hv.y + bc.y;
        o.z = a.z + sl * hv.z + bc.z;
        o.w = a.w + sl * hv.w + bc.w;
        *(float4*)&outpre[(size_t)row * D + c4 * 4] = o;
        sum.x += o.x; sum.y += o.y; sum.z += o.z; sum.w += o.w;
        sq.x = fmaf(o.x, o.x, sq.x); sq.y = fmaf(o.y, o.y, sq.y);
        sq.z = fmaf(o.z, o.z, sq.z); sq.w = fmaf(o.w, o.w, sq.w);
    }
    __shared__ float4 sS[256];
    __shared__ float4 qS[256];
    sS[tid] = sum; qS[tid] = sq;
    __syncthreads();
    if (ro == 0) {
        #pragma unroll
        for (int j = 1; j < 8; ++j) {
            float4 s2 = sS[j * 32 + c4];
            float4 q2 = qS[j * 32 + c4];
            sum.x += s2.x; sum.y += s2.y; sum.z += s2.z; sum.w += s2.w;
            sq.x += q2.x; sq.y += q2.y; sq.z += q2.z; sq.w += q2.w;
        }
        unsafeAtomicAdd(&sum_out[c4 * 4 + 0], sum.x);
        unsafeAtomicAdd(&sum_out[c4 * 4 + 1], sum.y);
        unsafeAtomicAdd(&sum_out[c4 * 4 + 2], sum.z);
        unsafeAtomicAdd(&sum_out[c4 * 4 + 3], sum.w);
        unsafeAtomicAdd(&sq_out[c4 * 4 + 0], sq.x);
        unsafeAtomicAdd(&sq_out[c4 * 4 + 1], sq.y);
        unsafeAtomicAdd(&sq_out[c4 * 4 + 2], sq.z);
        unsafeAtomicAdd(&sq_out[c4 * 4 + 3], sq.w);
    }
}

// ---------------- final: out = relu(out*scale2 + bias2), in place ----------------
__global__ void final_kernel(float* __restrict__ out, const float* __restrict__ scale,
                             const float* __restrict__ bias) {
    const int t = blockIdx.x * blockDim.x + threadIdx.x;
    const int c4 = t & 31;
    float4 sc = *(const float4*)&scale[c4 * 4];
    float4 bi = *(const float4*)&bias[c4 * 4];
    const int total = N_NODES * D / 4;
    const int stride = gridDim.x * blockDim.x;
    for (int i = t; i < total; i += stride) {
        float4 v = ((const float4*)out)[i];
        v.x = fmaxf(fmaf(v.x, sc.x, bi.x), 0.f);
        v.y = fmaxf(fmaf(v.y, sc.y, bi.y), 0.f);
        v.z = fmaxf(fmaf(v.z, sc.z, bi.z), 0.f);
        v.w = fmaxf(fmaf(v.w, sc.w, bi.w), 0.f);
        ((float4*)out)[i] = v;
    }
}

extern "C" void kernel_launch(void* const* d_in, const int* in_sizes, int n_in,
                              void* d_out, int out_size, void* d_ws, size_t ws_size,
                              hipStream_t stream) {
    const float* x      = (const float*)d_in[0];
    const int*   edge   = (const int*)d_in[1];      // [2][N_EDGES], row0=src, row1=dst
    const float* W_mlp  = (const float*)d_in[2];
    const float* b_mlp  = (const float*)d_in[3];
    const float* gamma1 = (const float*)d_in[4];
    const float* beta1  = (const float*)d_in[5];
    const float* W_conv = (const float*)d_in[6];
    const float* b_conv = (const float*)d_in[7];
    const float* gamma2 = (const float*)d_in[8];
    const float* beta2  = (const float*)d_in[9];
    float* out = (float*)d_out;

    float* ws = (float*)d_ws;
    float* h1   = ws;                                  // N*D
    float* h2   = ws + (size_t)N_NODES * D;            // N*D
    float* agg  = h1;                                  // alias: h1 is dead after gemm2
    float* deg  = ws + 2 * (size_t)N_NODES * D;        // N
    float* dinv = deg + N_NODES;                       // N
    float* stats = dinv + N_NODES;                     // 4*D
    float* sb    = stats + 4 * D;                      // 4*D
    float* sum1 = stats;         float* sq1 = stats + D;
    float* sum2 = stats + 2 * D; float* sq2 = stats + 3 * D;
    float* scale1 = sb;          float* bias1 = sb + D;
    float* scale2 = sb + 2 * D;  float* bias2 = sb + 3 * D;

    const int* srcI = edge;
    const int* dstI = edge + N_EDGES;

    init_kernel<<<(N_NODES + 255) / 256, 256, 0, stream>>>(deg, stats);
    deg_kernel<<<(N_EDGES + 255) / 256, 256, 0, stream>>>(dstI, deg);
    dinv_kernel<<<(N_NODES + 255) / 256, 256, 0, stream>>>(deg, dinv);

    gemm_kernel<false, true><<<(N_NODES + 63) / 64, 256, 0, stream>>>(
        x, W_mlp, nullptr, nullptr, b_mlp, h1, N_NODES);
    colstats_kernel<<<256, 256, 0, stream>>>(h1, sum1, sq1);
    sb_kernel<<<1, 128, 0, stream>>>(sum1, sq1, gamma1, beta1, scale1, bias1);

    gemm_kernel<true, false><<<(N_NODES + 63) / 64, 256, 0, stream>>>(
        h1, W_conv, scale1, bias1, nullptr, h2, N_NODES);

    zero_kernel<<<1024, 256, 0, stream>>>((float4*)agg, N_NODES * D / 4);
    agg_kernel<<<(N_EDGES * 32) / 256, 256, 0, stream>>>(srcI, dstI, dinv, h2, agg);

    post_kernel<<<256, 256, 0, stream>>>(agg, h2, dinv, b_conv, out, sum2, sq2);
    sb_kernel<<<1, 128, 0, stream>>>(sum2, sq2, gamma2, beta2, scale2, bias2);
    final_kernel<<<1024, 256, 0, stream>>>(out, scale2, bias2);
}

// Round 2
// 347.793 us; speedup vs baseline: 3.7289x; 3.7289x over previous
//
#include <hip/hip_runtime.h>
#include <math.h>

#define N_NODES 50000
#define N_EDGES 600000
#define D 128
#define BN_EPS 1e-5f
#define ELLW 64

// ---------------- init: cur = 0 (ELL cursors), stats = 0 ----------------
__global__ void init_kernel(int* __restrict__ cur, float* __restrict__ stats) {
    int i = blockIdx.x * blockDim.x + threadIdx.x;
    if (i < N_NODES) cur[i] = 0;
    if (i < 4 * D) stats[i] = 0.0f;
}

// ---------------- build ELL adjacency: dst -> list of src ----------------
__global__ void scatter_kernel(const int* __restrict__ srcI, const int* __restrict__ dstI,
                               int* __restrict__ cur, int* __restrict__ ell) {
    int e = blockIdx.x * blockDim.x + threadIdx.x;
    if (e >= N_EDGES) return;
    int d = dstI[e];
    int pos = atomicAdd(&cur[d], 1);
    if (pos < ELLW) ell[d * ELLW + pos] = srcI[e];
}

// ---------------- dinv = rsqrt(in_degree + 1)  (self-loop) ----------------
__global__ void dinv_kernel(const int* __restrict__ cur, float* __restrict__ dinv) {
    int i = blockIdx.x * blockDim.x + threadIdx.x;
    if (i < N_NODES) dinv[i] = rsqrtf((float)cur[i] + 1.0f);
}

// ---------------- GEMM: C = act(A) @ B (+bias) ----------------
// A: [M x 128], B: [128 x 128], C: [M x 128]
// BN: a -> relu(a*bn_scale[k] + bn_bias[k]) applied while staging A.
// Tile: 64 rows/block, 256 threads, each thread 8 rows x 4 cols.
template<bool BN, bool HAS_BIAS>
__global__ __launch_bounds__(256, 2) void gemm_kernel(
    const float* __restrict__ A, const float* __restrict__ B,
    const float* __restrict__ bn_scale, const float* __restrict__ bn_bias,
    const float* __restrict__ out_bias, float* __restrict__ C, int M)
{
    __shared__ float Bsh[128 * 128];   // 64 KB, whole B
    __shared__ float Ash[32][68];      // k-chunk of A, transposed, padded

    const int tid = threadIdx.x;
    const int tx = tid & 31;   // output col group (4 cols)
    const int ty = tid >> 5;   // output row group (8 rows)
    const int m0 = blockIdx.x * 64;

    // stage all of B
    {
        const float4* B4 = (const float4*)B;
        float4* Bs4 = (float4*)Bsh;
        #pragma unroll
        for (int i = 0; i < 16; ++i) {
            int idx = i * 256 + tid;
            Bs4[idx] = B4[idx];
        }
    }

    float acc[8][4];
    #pragma unroll
    for (int r = 0; r < 8; ++r)
        #pragma unroll
        for (int c = 0; c < 4; ++c) acc[r][c] = 0.0f;

    const int lr = tid >> 2;             // staging row 0..63
    int lrow = m0 + lr; if (lrow > M - 1) lrow = M - 1;   // clamp (stores guarded)
    const int cb = (tid & 3) * 8;        // staging col base within chunk

    for (int kc = 0; kc < 4; ++kc) {
        __syncthreads();
        #pragma unroll
        for (int h = 0; h < 2; ++h) {
            int c = cb + h * 4;
            int k = kc * 32 + c;
            float4 v = *(const float4*)&A[(size_t)lrow * 128 + k];
            if (BN) {
                v.x = fmaxf(v.x * bn_scale[k + 0] + bn_bias[k + 0], 0.0f);
                v.y = fmaxf(v.y * bn_scale[k + 1] + bn_bias[k + 1], 0.0f);
                v.z = fmaxf(v.z * bn_scale[k + 2] + bn_bias[k + 2], 0.0f);
                v.w = fmaxf(v.w * bn_scale[k + 3] + bn_bias[k + 3], 0.0f);
            }
            Ash[c + 0][lr] = v.x;
            Ash[c + 1][lr] = v.y;
            Ash[c + 2][lr] = v.z;
            Ash[c + 3][lr] = v.w;
        }
        __syncthreads();

        #pragma unroll
        for (int k = 0; k < 32; ++k) {
            float4 b = *(const float4*)&Bsh[(kc * 32 + k) * 128 + tx * 4];
            float4 a01 = *(const float4*)&Ash[k][ty * 8];
            float4 a23 = *(const float4*)&Ash[k][ty * 8 + 4];
            float a[8] = {a01.x, a01.y, a01.z, a01.w, a23.x, a23.y, a23.z, a23.w};
            #pragma unroll
            for (int r = 0; r < 8; ++r) {
                acc[r][0] = fmaf(a[r], b.x, acc[r][0]);
                acc[r][1] = fmaf(a[r], b.y, acc[r][1]);
                acc[r][2] = fmaf(a[r], b.z, acc[r][2]);
                acc[r][3] = fmaf(a[r], b.w, acc[r][3]);
            }
        }
    }

    float4 ob = make_float4(0.f, 0.f, 0.f, 0.f);
    if (HAS_BIAS) ob = *(const float4*)&out_bias[tx * 4];
    #pragma unroll
    for (int r = 0; r < 8; ++r) {
        int row = m0 + ty * 8 + r;
        if (row < M) {
            float4 o;
            o.x = acc[r][0] + ob.x;
            o.y = acc[r][1] + ob.y;
            o.z = acc[r][2] + ob.z;
            o.w = acc[r][3] + ob.w;
            *(float4*)&C[(size_t)row * 128 + tx * 4] = o;
        }
    }
}

// ---------------- column stats (sum, sumsq) over rows ----------------
__global__ __launch_bounds__(256) void colstats_kernel(const float* __restrict__ h,
        float* __restrict__ sum_out, float* __restrict__ sq_out) {
    const int tid = threadIdx.x;
    const int c4 = tid & 31;
    const int ro = tid >> 5;   // 0..7
    float4 sum = make_float4(0.f, 0.f, 0.f, 0.f);
    float4 sq  = make_float4(0.f, 0.f, 0.f, 0.f);
    for (int row = blockIdx.x * 8 + ro; row < N_NODES; row += gridDim.x * 8) {
        float4 v = *(const float4*)&h[(size_t)row * D + c4 * 4];
        sum.x += v.x; sum.y += v.y; sum.z += v.z; sum.w += v.w;
        sq.x = fmaf(v.x, v.x, sq.x); sq.y = fmaf(v.y, v.y, sq.y);
        sq.z = fmaf(v.z, v.z, sq.z); sq.w = fmaf(v.w, v.w, sq.w);
    }
    __shared__ float4 sS[256];
    __shared__ float4 qS[256];
    sS[tid] = sum; qS[tid] = sq;
    __syncthreads();
    if (ro == 0) {
        #pragma unroll
        for (int j = 1; j < 8; ++j) {
            float4 s2 = sS[j * 32 + c4];
            float4 q2 = qS[j * 32 + c4];
            sum.x += s2.x; sum.y += s2.y; sum.z += s2.z; sum.w += s2.w;
            sq.x += q2.x; sq.y += q2.y; sq.z += q2.z; sq.w += q2.w;
        }
        unsafeAtomicAdd(&sum_out[c4 * 4 + 0], sum.x);
        unsafeAtomicAdd(&sum_out[c4 * 4 + 1], sum.y);
        unsafeAtomicAdd(&sum_out[c4 * 4 + 2], sum.z);
        unsafeAtomicAdd(&sum_out[c4 * 4 + 3], sum.w);
        unsafeAtomicAdd(&sq_out[c4 * 4 + 0], sq.x);
        unsafeAtomicAdd(&sq_out[c4 * 4 + 1], sq.y);
        unsafeAtomicAdd(&sq_out[c4 * 4 + 2], sq.z);
        unsafeAtomicAdd(&sq_out[c4 * 4 + 3], sq.w);
    }
}

// ---------------- fold BN stats into scale/bias ----------------
__global__ void sb_kernel(const float* __restrict__ s_sum, const float* __restrict__ s_sq,
        const float* __restrict__ gamma, const float* __restrict__ beta,
        float* __restrict__ scale, float* __restrict__ bias) {
    int c = threadIdx.x;
    if (c < D) {
        const float inv_n = 1.0f / (float)N_NODES;
        float mean = s_sum[c] * inv_n;
        float var  = s_sq[c] * inv_n - mean * mean;
        float rstd = rsqrtf(var + BN_EPS);
        float sc = gamma[c] * rstd;
        scale[c] = sc;
        bias[c] = beta[c] - mean * sc;
    }
}

// ---------------- gather: out = dinv[d]*(sum_s dinv[s]*h2[s] + dinv[d]*h2[d]) + b_conv
//                  one wave per node; lane l handles cols {2l, 2l+1}; fused BN2 stats
__global__ __launch_bounds__(256) void gather_kernel(
    const int* __restrict__ ell, const int* __restrict__ cnt,
    const float* __restrict__ dinv, const float* __restrict__ h2,
    const float* __restrict__ b_conv, float* __restrict__ outpre,
    float* __restrict__ sum_out, float* __restrict__ sq_out)
{
    const int lane = threadIdx.x & 63;
    const int wid  = threadIdx.x >> 6;
    const float2 bc = *(const float2*)&b_conv[lane * 2];
    float2 sum = make_float2(0.f, 0.f);
    float2 sq  = make_float2(0.f, 0.f);

    for (int d = blockIdx.x * 4 + wid; d < N_NODES; d += gridDim.x * 4) {
        int c = cnt[d]; if (c > ELLW) c = ELLW;
        const float dd = dinv[d];
        float2 hv = *(const float2*)&h2[(size_t)d * D + lane * 2];
        float2 acc;
        acc.x = dd * hv.x;
        acc.y = dd * hv.y;
        const int base = d * ELLW;
        int j = 0;
        for (; j + 1 < c; j += 2) {
            int s0 = ell[base + j];
            int s1 = ell[base + j + 1];
            float w0 = dinv[s0];
            float w1 = dinv[s1];
            float2 v0 = *(const float2*)&h2[(size_t)s0 * D + lane * 2];
            float2 v1 = *(const float2*)&h2[(size_t)s1 * D + lane * 2];
            acc.x += w0 * v0.x + w1 * v1.x;
            acc.y += w0 * v0.y + w1 * v1.y;
        }
        if (j < c) {
            int s0 = ell[base + j];
            float w0 = dinv[s0];
            float2 v0 = *(const float2*)&h2[(size_t)s0 * D + lane * 2];
            acc.x += w0 * v0.x;
            acc.y += w0 * v0.y;
        }
        float2 o;
        o.x = fmaf(dd, acc.x, bc.x);
        o.y = fmaf(dd, acc.y, bc.y);
        *(float2*)&outpre[(size_t)d * D + lane * 2] = o;
        sum.x += o.x; sum.y += o.y;
        sq.x = fmaf(o.x, o.x, sq.x);
        sq.y = fmaf(o.y, o.y, sq.y);
    }

    __shared__ float2 sS[256];
    __shared__ float2 qS[256];
    sS[threadIdx.x] = sum; qS[threadIdx.x] = sq;
    __syncthreads();
    if (wid == 0) {
        #pragma unroll
        for (int w = 1; w < 4; ++w) {
            float2 s2 = sS[w * 64 + lane];
            float2 q2 = qS[w * 64 + lane];
            sum.x += s2.x; sum.y += s2.y;
            sq.x += q2.x; sq.y += q2.y;
        }
        unsafeAtomicAdd(&sum_out[lane * 2 + 0], sum.x);
        unsafeAtomicAdd(&sum_out[lane * 2 + 1], sum.y);
        unsafeAtomicAdd(&sq_out[lane * 2 + 0], sq.x);
        unsafeAtomicAdd(&sq_out[lane * 2 + 1], sq.y);
    }
}

// ---------------- final: out = relu(out*scale2 + bias2), in place ----------------
__global__ void final_kernel(float* __restrict__ out, const float* __restrict__ scale,
                             const float* __restrict__ bias) {
    const int t = blockIdx.x * blockDim.x + threadIdx.x;
    const int c4 = t & 31;
    float4 sc = *(const float4*)&scale[c4 * 4];
    float4 bi = *(const float4*)&bias[c4 * 4];
    const int total = N_NODES * D / 4;
    const int stride = gridDim.x * blockDim.x;
    for (int i = t; i < total; i += stride) {
        float4 v = ((const float4*)out)[i];
        v.x = fmaxf(fmaf(v.x, sc.x, bi.x), 0.f);
        v.y = fmaxf(fmaf(v.y, sc.y, bi.y), 0.f);
        v.z = fmaxf(fmaf(v.z, sc.z, bi.z), 0.f);
        v.w = fmaxf(fmaf(v.w, sc.w, bi.w), 0.f);
        ((float4*)out)[i] = v;
    }
}

extern "C" void kernel_launch(void* const* d_in, const int* in_sizes, int n_in,
                              void* d_out, int out_size, void* d_ws, size_t ws_size,
                              hipStream_t stream) {
    const float* x      = (const float*)d_in[0];
    const int*   edge   = (const int*)d_in[1];      // [2][N_EDGES], row0=src, row1=dst
    const float* W_mlp  = (const float*)d_in[2];
    const float* b_mlp  = (const float*)d_in[3];
    const float* gamma1 = (const float*)d_in[4];
    const float* beta1  = (const float*)d_in[5];
    const float* W_conv = (const float*)d_in[6];
    const float* b_conv = (const float*)d_in[7];
    const float* gamma2 = (const float*)d_in[8];
    const float* beta2  = (const float*)d_in[9];
    float* out = (float*)d_out;

    float* ws = (float*)d_ws;
    float* h1   = ws;                                  // N*D floats
    float* h2   = ws + (size_t)N_NODES * D;            // N*D floats
    int*   ell  = (int*)h1;                            // alias: h1 dead after gemm2 (50K*64 ints = 12.8MB < 25.6MB)
    float* extra = ws + 2 * (size_t)N_NODES * D;
    int*   cur  = (int*)extra;                         // N ints (ELL cursors / in-degree)
    float* dinv = extra + N_NODES;                     // N floats
    float* stats = extra + 2 * N_NODES;                // 4*D
    float* sb    = stats + 4 * D;                      // 4*D
    float* sum1 = stats;         float* sq1 = stats + D;
    float* sum2 = stats + 2 * D; float* sq2 = stats + 3 * D;
    float* scale1 = sb;          float* bias1 = sb + D;
    float* scale2 = sb + 2 * D;  float* bias2 = sb + 3 * D;

    const int* srcI = edge;
    const int* dstI = edge + N_EDGES;

    init_kernel<<<(N_NODES + 255) / 256, 256, 0, stream>>>(cur, stats);

    gemm_kernel<false, true><<<(N_NODES + 63) / 64, 256, 0, stream>>>(
        x, W_mlp, nullptr, nullptr, b_mlp, h1, N_NODES);
    colstats_kernel<<<256, 256, 0, stream>>>(h1, sum1, sq1);
    sb_kernel<<<1, 128, 0, stream>>>(sum1, sq1, gamma1, beta1, scale1, bias1);

    gemm_kernel<true, false><<<(N_NODES + 63) / 64, 256, 0, stream>>>(
        h1, W_conv, scale1, bias1, nullptr, h2, N_NODES);

    // h1 is dead now: build ELL adjacency in its place
    scatter_kernel<<<(N_EDGES + 255) / 256, 256, 0, stream>>>(srcI, dstI, cur, ell);
    dinv_kernel<<<(N_NODES + 255) / 256, 256, 0, stream>>>(cur, dinv);

    gather_kernel<<<1024, 256, 0, stream>>>(ell, cur, dinv, h2, b_conv, out, sum2, sq2);

    sb_kernel<<<1, 128, 0, stream>>>(sum2, sq2, gamma2, beta2, scale2, bias2);
    final_kernel<<<1024, 256, 0, stream>>>(out, scale2, bias2);
}